// Round 3
// baseline (7997.701 us; speedup 1.0000x reference)
//
#include <hip/hip_runtime.h>
#include <math.h>

typedef unsigned short u16;
typedef unsigned long long u64;
typedef __bf16 bf16x8 __attribute__((ext_vector_type(8)));
typedef float f32x4 __attribute__((ext_vector_type(4)));

#define AS1(p) ((const __attribute__((address_space(1))) void*)(p))
#define AS3(p) ((__attribute__((address_space(3))) void*)(p))

__device__ __forceinline__ u16 f2bf(float x) {
  unsigned u = __float_as_uint(x);
  u = u + 0x7fffu + ((u >> 16) & 1u);
  return (u16)(u >> 16);
}
__device__ __forceinline__ float bflo(unsigned x){ return __uint_as_float(x << 16); }
__device__ __forceinline__ float bfhi(unsigned x){ return __uint_as_float(x & 0xffff0000u); }

// ---------------- generic f32 -> bf16 ----------------
__global__ __launch_bounds__(256) void f2bf_kernel(const float* __restrict__ in,
                                                   u16* __restrict__ out, int n) {
  int i = blockIdx.x * 256 + threadIdx.x;
  int stride = gridDim.x * 256;
  for (; i < n; i += stride) out[i] = f2bf(in[i]);
}

// ---------------- embedding gather -> bf16 ----------------
__global__ __launch_bounds__(256) void gather_kernel(const int* __restrict__ ids,
                                                     const float* __restrict__ embW,
                                                     u16* __restrict__ out) {
  int row = blockIdx.x;                       // token index b*1024+s
  long base = (long)ids[row] << 9;            // *512
  long obase = (long)row << 9;
  for (int c = threadIdx.x; c < 512; c += 256) out[obase + c] = f2bf(embW[base + c]);
}

// ---------------- bf16 MFMA GEMM: C[M,N] = A[M,K] @ Bt[N,K]^T (+bias[N]) ------
__global__ __launch_bounds__(256) void gemm_bt(const u16* __restrict__ A,
                                               const u16* __restrict__ Bt,
                                               float* __restrict__ C,
                                               const float* __restrict__ bias,
                                               int M, int N, int K) {
  __shared__ __attribute__((aligned(16))) u16 lA[128 * 32];
  __shared__ __attribute__((aligned(16))) u16 lB[128 * 32];
  const int tid = threadIdx.x;
  const int w = tid >> 6, l = tid & 63;
  const int bn = blockIdx.x, bm = blockIdx.y;
  const int frow = l & 15, fq = l >> 4;
  const int wm = (w >> 1) * 64, wn = (w & 1) * 64;
  f32x4 acc[16];
#pragma unroll
  for (int i = 0; i < 16; i++) acc[i] = (f32x4){0.f, 0.f, 0.f, 0.f};

  const long a0 = (long)bm * 128 * K;
  const long b0 = (long)bn * 128 * K;
  for (int k0 = 0; k0 < K; k0 += 32) {
#pragma unroll
    for (int p = 0; p < 2; p++) {
      int q = (p * 4 + w) * 64 + l;          // chunk 0..511
      int r = q >> 2, c = (q & 3) << 3;      // row, col-offset (ushorts)
      __builtin_amdgcn_global_load_lds(AS1(A + a0 + (long)r * K + k0 + c),
                                       AS3(&lA[(p * 4 + w) * 512]), 16, 0, 0);
      __builtin_amdgcn_global_load_lds(AS1(Bt + b0 + (long)r * K + k0 + c),
                                       AS3(&lB[(p * 4 + w) * 512]), 16, 0, 0);
    }
    __syncthreads();
    bf16x8 af[4], bfv[4];
#pragma unroll
    for (int i = 0; i < 4; i++) af[i]  = *(const bf16x8*)&lA[(wm + i * 16 + frow) * 32 + fq * 8];
#pragma unroll
    for (int j = 0; j < 4; j++) bfv[j] = *(const bf16x8*)&lB[(wn + j * 16 + frow) * 32 + fq * 8];
#pragma unroll
    for (int i = 0; i < 4; i++)
#pragma unroll
      for (int j = 0; j < 4; j++)
        acc[i * 4 + j] = __builtin_amdgcn_mfma_f32_16x16x32_bf16(af[i], bfv[j], acc[i * 4 + j], 0, 0, 0);
    __syncthreads();
  }
#pragma unroll
  for (int i = 0; i < 4; i++) {
    int row = bm * 128 + wm + i * 16 + fq * 4;
#pragma unroll
    for (int j = 0; j < 4; j++) {
      int col = bn * 128 + wn + j * 16 + frow;
      float bv = bias ? bias[col] : 0.f;
#pragma unroll
      for (int r = 0; r < 4; r++)
        C[(long)(row + r) * N + col] = acc[i * 4 + j][r] + bv;
    }
  }
}

// ---------------- GRU: persistent grid over ALL 256 CUs ----------------------
// Round-2 counters showed the 64-WG version concentrated ~3100 LDS-pipe cycles
// per step on each of only 64 active CUs (5.0e7 SQ_LDS_BANK_CONFLICT, 6.2%
// occupancy). This version spreads compute over 256 WGs (4 feats each, 1/CU):
//  - per-CU LDS traffic drops 4x AND becomes conflict-free: each ds_read_b128
//    is a wave-contiguous 1KB access (lane l reads 16B at byte 16*l).
//  - barrier arrival is 256 PLAIN u32 epoch stores to distinct slots (no RMW
//    serialization at the atomic unit). Poll: wave 0's 64 lanes each load 2
//    u64 (covering all 256 epochs) and ballot. Epochs are monotone; check is
//    >= target, so a WG running one step ahead cannot deadlock the check.
// Ordering (unchanged from proven scheme): h stores + epoch store both issue
// from wave 0; s_waitcnt(0) drains h to the IF-cache coherence point before
// the epoch store. All cross-WG data moves via agent-scope relaxed atomics
// (bypass non-coherent per-XCD L1/L2). No __threadfence -> no L2 flushes.
__global__ __launch_bounds__(256) void gru_kernel(const u16* __restrict__ Whh,
                                                  const float* __restrict__ b_hh,
                                                  const float* __restrict__ xproj,
                                                  u16* __restrict__ hbuf,   // [2][2][1024] u16
                                                  float* __restrict__ states, // [2][1024][1024]
                                                  unsigned* __restrict__ ep) { // [256] epochs
  __shared__ __attribute__((aligned(16))) u16 lW[12 * 1024];
  __shared__ float hgs[2][12];
  const int g = blockIdx.x;
  const int tid = threadIdx.x;
  const int f0 = g * 4;
  // stage 12 W_hh rows: lr = gate*4 + ff  ->  global row gate*1024 + f0 + ff
  for (int c = tid; c < 1536; c += 256) {            // 1536 chunks of 8 ushorts
    int lr = c >> 7, off = (c & 127) << 3;
    *(uint4*)(lW + lr * 1024 + off) =
        *(const uint4*)(Whh + ((long)((lr >> 2) << 10) + f0 + (lr & 3)) * 1024 + off);
  }
  // per-lane hidden-gate biases for the tail (loaded once)
  float bhr = 0.f, bhz = 0.f, bhn = 0.f;
  if (tid < 8) {
    int ff = tid & 3;
    bhr = b_hh[f0 + ff]; bhz = b_hh[1024 + f0 + ff]; bhn = b_hh[2048 + f0 + ff];
  }
  __syncthreads();

  const int w = tid >> 6, l = tid & 63;
  const int b = w >> 1, half = w & 1;                // wave handles batch b, rows half*6..+5
  float hp = 0.f;                                    // fp32 h owned by tid<8

  for (int t = 0; t < 1024; t++) {
    // prefetch x-gates (independent of h; in flight during the dots)
    float xr = 0.f, xz = 0.f, xn = 0.f;
    if (tid < 8) {
      int bb = tid >> 2, ff = tid & 3;
      const float* xb = xproj + (long)((bb << 10) + t) * 3072 + f0 + ff;
      xr = xb[0]; xz = xb[1024]; xn = xb[2048];
    }
    // coherent h load: lane l covers cols {8l..8l+7} u {512+8l..+7} (4 u64, coalesced)
    const u64* h64 = (const u64*)(hbuf + ((t & 1) << 11) + (b << 10));
    u64 qa0 = __hip_atomic_load(h64 + (l << 1),       __ATOMIC_RELAXED, __HIP_MEMORY_SCOPE_AGENT);
    u64 qa1 = __hip_atomic_load(h64 + (l << 1) + 1,   __ATOMIC_RELAXED, __HIP_MEMORY_SCOPE_AGENT);
    u64 qb0 = __hip_atomic_load(h64 + 128 + (l << 1), __ATOMIC_RELAXED, __HIP_MEMORY_SCOPE_AGENT);
    u64 qb1 = __hip_atomic_load(h64 + 129 + (l << 1), __ATOMIC_RELAXED, __HIP_MEMORY_SCOPE_AGENT);
    float hA[8], hB[8];
    {
      unsigned a0 = (unsigned)qa0, a1 = (unsigned)(qa0 >> 32);
      unsigned a2 = (unsigned)qa1, a3 = (unsigned)(qa1 >> 32);
      hA[0]=bflo(a0); hA[1]=bfhi(a0); hA[2]=bflo(a1); hA[3]=bfhi(a1);
      hA[4]=bflo(a2); hA[5]=bfhi(a2); hA[6]=bflo(a3); hA[7]=bfhi(a3);
      unsigned b0 = (unsigned)qb0, b1 = (unsigned)(qb0 >> 32);
      unsigned b2 = (unsigned)qb1, b3 = (unsigned)(qb1 >> 32);
      hB[0]=bflo(b0); hB[1]=bfhi(b0); hB[2]=bflo(b1); hB[3]=bfhi(b1);
      hB[4]=bflo(b2); hB[5]=bfhi(b2); hB[6]=bflo(b3); hB[7]=bfhi(b3);
    }
    // 6 full-wave row-dots; each ds_read_b128 is 1KB wave-contiguous (conflict-free)
#pragma unroll
    for (int r = 0; r < 6; r++) {
      int lr = half * 6 + r;
      uint4 w0 = *(const uint4*)(lW + lr * 1024 + (l << 3));
      uint4 w1 = *(const uint4*)(lW + lr * 1024 + 512 + (l << 3));
      float s = hA[0]*bflo(w0.x) + hA[1]*bfhi(w0.x)
              + hA[2]*bflo(w0.y) + hA[3]*bfhi(w0.y)
              + hA[4]*bflo(w0.z) + hA[5]*bfhi(w0.z)
              + hA[6]*bflo(w0.w) + hA[7]*bfhi(w0.w)
              + hB[0]*bflo(w1.x) + hB[1]*bfhi(w1.x)
              + hB[2]*bflo(w1.y) + hB[3]*bfhi(w1.y)
              + hB[4]*bflo(w1.z) + hB[5]*bfhi(w1.z)
              + hB[6]*bflo(w1.w) + hB[7]*bfhi(w1.w);
      s += __shfl_down(s, 32, 64);
      s += __shfl_down(s, 16, 64);
      s += __shfl_down(s, 8, 64);
      s += __shfl_down(s, 4, 64);
      s += __shfl_down(s, 2, 64);
      s += __shfl_down(s, 1, 64);
      if (l == 0) hgs[b][lr] = s;
    }
    __syncthreads();
    if (tid < 8) {
      int bb = tid >> 2, ff = tid & 3, f = f0 + ff;
      float rr = 1.f / (1.f + expf(-(xr + hgs[bb][ff] + bhr)));
      float zz = 1.f / (1.f + expf(-(xz + hgs[bb][4 + ff] + bhz)));
      float nn = tanhf(xn + rr * (hgs[bb][8 + ff] + bhn));
      float hnew = (1.f - zz) * nn + zz * hp;
      hp = hnew;
      states[(long)((bb << 10) + t) * 1024 + f] = hnew;
      __hip_atomic_store(hbuf + (((t + 1) & 1) << 11) + (bb << 10) + f, f2bf(hnew),
                         __ATOMIC_RELAXED, __HIP_MEMORY_SCOPE_AGENT);
    }
    if (tid == 0) {
      __builtin_amdgcn_s_waitcnt(0);   // drain wave-0 stores (h + states) to coherence point
      __hip_atomic_store(ep + g, (unsigned)(t + 1), __ATOMIC_RELAXED, __HIP_MEMORY_SCOPE_AGENT);
    }
    if (tid < 64) {                    // wave 0 polls all 256 epochs (2 u64 per lane)
      const u64* e64 = (const u64*)ep;
      unsigned tgt = (unsigned)(t + 1);
      for (;;) {
        u64 ea = __hip_atomic_load(e64 + tid,      __ATOMIC_RELAXED, __HIP_MEMORY_SCOPE_AGENT);
        u64 eb = __hip_atomic_load(e64 + 64 + tid, __ATOMIC_RELAXED, __HIP_MEMORY_SCOPE_AGENT);
        bool ok = ((unsigned)ea >= tgt) & ((unsigned)(ea >> 32) >= tgt)
                & ((unsigned)eb >= tgt) & ((unsigned)(eb >> 32) >= tgt);
        if (__all(ok)) break;
        __builtin_amdgcn_s_sleep(1);
      }
    }
    __syncthreads();
  }
}

// ---------------- mixed + RMSnorm + gate -------------------------------------
__global__ __launch_bounds__(256) void mix_kernel(const float* __restrict__ states,
                                                  const float* __restrict__ inres,
                                                  const float* __restrict__ gate_W,
                                                  const float* __restrict__ gate_b,
                                                  const float* __restrict__ rlam,
                                                  const float* __restrict__ ilam,
                                                  const float* __restrict__ mscale,
                                                  u16* __restrict__ mixed_bf,
                                                  float* __restrict__ gate6) {
  const int row = blockIdx.x, tid = threadIdx.x, w = tid >> 6, l = tid & 63;
  __shared__ float red[16];
  float rl = rlam[0], il = ilam[0];
  const float* sr = states + (long)row * 1024;
  const float* ir = inres + (long)row * 1024;
  float m[4]; float ss = 0.f;
#pragma unroll
  for (int u = 0; u < 4; u++) {
    int h = (u << 8) + tid;
    m[u] = rl * sr[h] + il * ir[h];
    ss += m[u] * m[u];
  }
#pragma unroll
  for (int off = 32; off > 0; off >>= 1) ss += __shfl_down(ss, off, 64);
  if (l == 0) red[w] = ss;
  __syncthreads();
  float tot = red[0] + red[1] + red[2] + red[3];
  float scale = rsqrtf(tot * (1.f / 1024.f) + 1.1920929e-07f);
  float gd = 0.f;
#pragma unroll
  for (int u = 0; u < 4; u++) {
    int h = (u << 8) + tid;
    float v = m[u] * scale;
    mixed_bf[(long)row * 1024 + h] = f2bf(v);
    gd += v * gate_W[h];
  }
#pragma unroll
  for (int off = 32; off > 0; off >>= 1) gd += __shfl_down(gd, off, 64);
  if (l == 0) red[8 + w] = gd;
  __syncthreads();
  if (tid == 0) {
    float gsum = red[8] + red[9] + red[10] + red[11] + gate_b[0];
    gate6[row] = (1.f / (1.f + expf(-gsum))) * mscale[0];
  }
}

// ---------------- strictly-causal softmax attention -> gated -----------------
__global__ __launch_bounds__(256) void attn_kernel(const float* __restrict__ q,
                                                   const float* __restrict__ k,
                                                   const float* __restrict__ gate6,
                                                   float* __restrict__ gated) {
  const int bi = blockIdx.x; const int b = bi >> 10, i = bi & 1023;
  if (i == 0) return;
  const int tid = threadIdx.x, w = tid >> 6, l = tid & 63;
  __shared__ float sc[1024];
  __shared__ float red[16];
  const float4 qv = *(const float4*)(q + (long)bi * 256 + (l << 2));
  for (int j = w; j < i; j += 4) {
    float4 kv = *(const float4*)(k + ((long)(b << 10) + j) * 256 + (l << 2));
    float s = qv.x * kv.x + qv.y * kv.y + qv.z * kv.z + qv.w * kv.w;
#pragma unroll
    for (int off = 32; off > 0; off >>= 1) s += __shfl_down(s, off, 64);
    if (l == 0) sc[j] = s * 0.0625f;       // 1/sqrt(256)
  }
  __syncthreads();
  float mx = -3.0e38f;
  for (int j = tid; j < i; j += 256) mx = fmaxf(mx, sc[j]);
#pragma unroll
  for (int off = 32; off > 0; off >>= 1) mx = fmaxf(mx, __shfl_down(mx, off, 64));
  if (l == 0) red[w] = mx;
  __syncthreads();
  mx = fmaxf(fmaxf(red[0], red[1]), fmaxf(red[2], red[3]));
  float sum = 0.f;
  for (int j = tid; j < i; j += 256) { float e = expf(sc[j] - mx); sc[j] = e; sum += e; }
#pragma unroll
  for (int off = 32; off > 0; off >>= 1) sum += __shfl_down(sum, off, 64);
  if (l == 0) red[8 + w] = sum;
  __syncthreads();
  sum = red[8] + red[9] + red[10] + red[11];
  float invs = gate6[bi] / sum;
  float* grow = gated + (long)bi * 1024;
  for (int j = tid; j < i; j += 256) grow[j] = sc[j] * invs;
}

// ---------------- scatter-add into logits ------------------------------------
__global__ __launch_bounds__(256) void scatter_kernel(const int* __restrict__ ids,
                                                      const float* __restrict__ gated,
                                                      float* __restrict__ out) {
  const int bi = blockIdx.x; const int b = bi >> 10, i = bi & 1023;
  const float* g = gated + (long)bi * 1024;
  float* o = out + (long)bi * 32000;
  const int* idr = ids + (b << 10);
  for (int j = threadIdx.x; j < i; j += 256)
    atomicAdd(o + idr[j], g[j]);
}

extern "C" void kernel_launch(void* const* d_in, const int* in_sizes, int n_in,
                              void* d_out, int out_size, void* d_ws, size_t ws_size,
                              hipStream_t stream) {
  const int*   ids      = (const int*)  d_in[0];
  const float* emb_W    = (const float*)d_in[1];
  const float* W_ih     = (const float*)d_in[2];
  const float* W_hh     = (const float*)d_in[3];
  const float* b_ih     = (const float*)d_in[4];
  const float* b_hh     = (const float*)d_in[5];
  const float* in_res_W = (const float*)d_in[6];
  const float* q_W      = (const float*)d_in[7];
  const float* q_b      = (const float*)d_in[8];
  const float* k_W      = (const float*)d_in[9];
  const float* k_b      = (const float*)d_in[10];
  const float* gate_W   = (const float*)d_in[11];
  const float* gate_b   = (const float*)d_in[12];
  const float* h2e_W    = (const float*)d_in[13];
  const float* h2e_b    = (const float*)d_in[14];
  const float* out_bias = (const float*)d_in[15];
  const float* mscale   = (const float*)d_in[16];
  const float* rlam     = (const float*)d_in[17];
  const float* ilam     = (const float*)d_in[18];
  float* out = (float*)d_out;

  char* p = (char*)d_ws;
  auto alloc = [&](size_t b) { char* r = p; p += (b + 255) & ~(size_t)255; return (void*)r; };
  u16*   emb_bf   = (u16*)  alloc((size_t)2048 * 512 * 2);
  u16*   Wih_bf   = (u16*)  alloc((size_t)3072 * 512 * 2);
  u16*   inresW_bf= (u16*)  alloc((size_t)1024 * 512 * 2);
  u16*   Whh_bf   = (u16*)  alloc((size_t)3072 * 1024 * 2);
  u16*   h2e_bf   = (u16*)  alloc((size_t)512 * 1024 * 2);
  u16*   qW_bf    = (u16*)  alloc((size_t)256 * 1024 * 2);
  u16*   kW_bf    = (u16*)  alloc((size_t)256 * 1024 * 2);
  u16*   embW_bf  = (u16*)  alloc((size_t)32000 * 512 * 2);
  float* xproj    = (float*)alloc((size_t)2048 * 3072 * 4);
  float* inres    = (float*)alloc((size_t)2048 * 1024 * 4);
  float* states   = (float*)alloc((size_t)2048 * 1024 * 4);
  u16*   mixed_bf = (u16*)  alloc((size_t)2048 * 1024 * 2);
  float* tbuf     = (float*)alloc((size_t)2048 * 512 * 4);
  u16*   t_bf     = (u16*)  alloc((size_t)2048 * 512 * 2);
  float* qbuf     = (float*)alloc((size_t)2048 * 256 * 4);
  float* kbuf     = (float*)alloc((size_t)2048 * 256 * 4);
  float* gated    = (float*)alloc((size_t)2048 * 1024 * 4);
  float* gate6    = (float*)alloc((size_t)2048 * 4);
  u16*   hbuf     = (u16*)  alloc((size_t)2 * 2 * 1024 * 2);
  unsigned* epoch = (unsigned*)alloc(1024);

  hipMemsetAsync(hbuf, 0, 2 * 2 * 1024 * 2, stream);
  hipMemsetAsync(epoch, 0, 1024, stream);

  // weight / input conversions to bf16
  f2bf_kernel<<<1024, 256, 0, stream>>>(W_ih, Wih_bf, 3072 * 512);
  f2bf_kernel<<<512, 256, 0, stream>>>(in_res_W, inresW_bf, 1024 * 512);
  f2bf_kernel<<<1024, 256, 0, stream>>>(W_hh, Whh_bf, 3072 * 1024);
  f2bf_kernel<<<512, 256, 0, stream>>>(h2e_W, h2e_bf, 512 * 1024);
  f2bf_kernel<<<256, 256, 0, stream>>>(q_W, qW_bf, 256 * 1024);
  f2bf_kernel<<<256, 256, 0, stream>>>(k_W, kW_bf, 256 * 1024);
  f2bf_kernel<<<2048, 256, 0, stream>>>(emb_W, embW_bf, 32000 * 512);
  gather_kernel<<<2048, 256, 0, stream>>>(ids, emb_W, emb_bf);

  // x_proj = emb @ W_ih.T + b_ih ;  inres = emb @ in_res_W.T
  gemm_bt<<<dim3(24, 16), 256, 0, stream>>>(emb_bf, Wih_bf, xproj, b_ih, 2048, 3072, 512);
  gemm_bt<<<dim3(8, 16), 256, 0, stream>>>(emb_bf, inresW_bf, inres, nullptr, 2048, 1024, 512);

  // sequential GRU over S=1024 (persistent grid on all 256 CUs, epoch barrier)
  gru_kernel<<<256, 256, 0, stream>>>(Whh_bf, b_hh, xproj, hbuf, states, epoch);

  // mixed + RMS + gate
  mix_kernel<<<2048, 256, 0, stream>>>(states, inres, gate_W, gate_b, rlam, ilam, mscale,
                                       mixed_bf, gate6);

  // q, k, t projections
  gemm_bt<<<dim3(2, 16), 256, 0, stream>>>(mixed_bf, qW_bf, qbuf, q_b, 2048, 256, 1024);
  gemm_bt<<<dim3(2, 16), 256, 0, stream>>>(mixed_bf, kW_bf, kbuf, k_b, 2048, 256, 1024);
  gemm_bt<<<dim3(4, 16), 256, 0, stream>>>(mixed_bf, h2e_bf, tbuf, h2e_b, 2048, 512, 1024);
  f2bf_kernel<<<512, 256, 0, stream>>>(tbuf, t_bf, 2048 * 512);

  // attention -> gated
  attn_kernel<<<2048, 256, 0, stream>>>(qbuf, kbuf, gate6, gated);

  // base logits (big GEMM, writes all of d_out) then scatter-add
  gemm_bt<<<dim3(250, 16), 256, 0, stream>>>(t_bf, embW_bf, out, out_bias, 2048, 32000, 512);
  scatter_kernel<<<2048, 256, 0, stream>>>(ids, gated, out);
}

// Round 5
// 7321.444 us; speedup vs baseline: 1.0924x; 1.0924x over previous
//
#include <hip/hip_runtime.h>
#include <math.h>

typedef unsigned short u16;
typedef unsigned long long u64;
typedef __bf16 bf16x8 __attribute__((ext_vector_type(8)));
typedef float f32x4 __attribute__((ext_vector_type(4)));

#define AS1(p) ((const __attribute__((address_space(1))) void*)(p))
#define AS3(p) ((__attribute__((address_space(3))) void*)(p))

__device__ __forceinline__ u16 f2bf(float x) {
  unsigned u = __float_as_uint(x);
  u = u + 0x7fffu + ((u >> 16) & 1u);
  return (u16)(u >> 16);
}
__device__ __forceinline__ float bflo(unsigned x){ return __uint_as_float(x << 16); }
__device__ __forceinline__ float bfhi(unsigned x){ return __uint_as_float(x & 0xffff0000u); }

// ---------------- generic f32 -> bf16 ----------------
__global__ __launch_bounds__(256) void f2bf_kernel(const float* __restrict__ in,
                                                   u16* __restrict__ out, int n) {
  int i = blockIdx.x * 256 + threadIdx.x;
  int stride = gridDim.x * 256;
  for (; i < n; i += stride) out[i] = f2bf(in[i]);
}

// ---------------- embedding gather -> bf16 ----------------
__global__ __launch_bounds__(256) void gather_kernel(const int* __restrict__ ids,
                                                     const float* __restrict__ embW,
                                                     u16* __restrict__ out) {
  int row = blockIdx.x;                       // token index b*1024+s
  long base = (long)ids[row] << 9;            // *512
  long obase = (long)row << 9;
  for (int c = threadIdx.x; c < 512; c += 256) out[obase + c] = f2bf(embW[base + c]);
}

// ---------------- bf16 MFMA GEMM: C[M,N] = A[M,K] @ Bt[N,K]^T (+bias[N]) ------
__global__ __launch_bounds__(256) void gemm_bt(const u16* __restrict__ A,
                                               const u16* __restrict__ Bt,
                                               float* __restrict__ C,
                                               const float* __restrict__ bias,
                                               int M, int N, int K) {
  __shared__ __attribute__((aligned(16))) u16 lA[128 * 32];
  __shared__ __attribute__((aligned(16))) u16 lB[128 * 32];
  const int tid = threadIdx.x;
  const int w = tid >> 6, l = tid & 63;
  const int bn = blockIdx.x, bm = blockIdx.y;
  const int frow = l & 15, fq = l >> 4;
  const int wm = (w >> 1) * 64, wn = (w & 1) * 64;
  f32x4 acc[16];
#pragma unroll
  for (int i = 0; i < 16; i++) acc[i] = (f32x4){0.f, 0.f, 0.f, 0.f};

  const long a0 = (long)bm * 128 * K;
  const long b0 = (long)bn * 128 * K;
  for (int k0 = 0; k0 < K; k0 += 32) {
#pragma unroll
    for (int p = 0; p < 2; p++) {
      int q = (p * 4 + w) * 64 + l;          // chunk 0..511
      int r = q >> 2, c = (q & 3) << 3;      // row, col-offset (ushorts)
      __builtin_amdgcn_global_load_lds(AS1(A + a0 + (long)r * K + k0 + c),
                                       AS3(&lA[(p * 4 + w) * 512]), 16, 0, 0);
      __builtin_amdgcn_global_load_lds(AS1(Bt + b0 + (long)r * K + k0 + c),
                                       AS3(&lB[(p * 4 + w) * 512]), 16, 0, 0);
    }
    __syncthreads();
    bf16x8 af[4], bfv[4];
#pragma unroll
    for (int i = 0; i < 4; i++) af[i]  = *(const bf16x8*)&lA[(wm + i * 16 + frow) * 32 + fq * 8];
#pragma unroll
    for (int j = 0; j < 4; j++) bfv[j] = *(const bf16x8*)&lB[(wn + j * 16 + frow) * 32 + fq * 8];
#pragma unroll
    for (int i = 0; i < 4; i++)
#pragma unroll
      for (int j = 0; j < 4; j++)
        acc[i * 4 + j] = __builtin_amdgcn_mfma_f32_16x16x32_bf16(af[i], bfv[j], acc[i * 4 + j], 0, 0, 0);
    __syncthreads();
  }
#pragma unroll
  for (int i = 0; i < 4; i++) {
    int row = bm * 128 + wm + i * 16 + fq * 4;
#pragma unroll
    for (int j = 0; j < 4; j++) {
      int col = bn * 128 + wn + j * 16 + frow;
      float bv = bias ? bias[col] : 0.f;
#pragma unroll
      for (int r = 0; r < 4; r++)
        C[(long)(row + r) * N + col] = acc[i * 4 + j][r] + bv;
    }
  }
}

// ---------------- GRU: persistent grid, BARRIER-FREE (flag-in-data) ----------
// R3 post-mortem: the device barrier (flags at the IF-cache coherence point)
// cost ~3-6 us/step and scaled ~linearly with participants -- it is pure
// indirection on top of the data consumers actually want. This version fuses
// sync into the data: each h element is published as a u32 = (tag<<16)|bf16,
// tag = step index. Consumers poll exactly the 64B/lane of h they need and
// proceed when their own words are fresh. No flag array, no s_waitcnt on the
// critical path (tag travels atomically with its value), no release hop.
//
// Parity double-buffer safety: a producer writes h_{t+2} (parity t) only
// after it observed ALL of h_{t+1}, which required every WG to publish
// h_{t+1}, which (via each WG's __syncthreads between dot-writes and gate
// reads) required every wave to have finished its step-t poll -- and the
// poll loads ARE the h_t data reads (tag travels in the same atomic word),
// so no reader can still need h_t when tag t+2 appears. Tags are monotone;
// check is (tag >= t).
//
// 64 WGs x 512 thr (96KB LDS -> 1 WG/CU, trivially co-resident).
// WG g owns feats f0=16g..+15 (48 W_hh rows). Wave w: batch b=w>>2,
// rows (w&3)*12..+11, full-wave conflict-free row-dots (2x ds_read_b128 of
// contiguous 1KB per row), h held in 16 registers loaded once per step.
__global__ __launch_bounds__(512) void gru_kernel(const u16* __restrict__ Whh,
                                                  const float* __restrict__ b_hh,
                                                  const float* __restrict__ xproj,
                                                  unsigned* __restrict__ hbuf, // [2][2][1024] u32 tagged
                                                  float* __restrict__ states) { // [2][1024][1024]
  __shared__ __attribute__((aligned(16))) u16 lW[48 * 1024];
  __shared__ float hgs[2][48];
  const int g = blockIdx.x;
  const int tid = threadIdx.x;
  const int f0 = g * 16;
  // stage 48 W_hh rows: lr = gate*16 + ff  ->  global row gate*1024 + f0 + ff
  for (int c = tid; c < 6144; c += 512) {            // 6144 chunks of 8 ushorts
    int lr = c >> 7, off = (c & 127) << 3;
    *(uint4*)(lW + lr * 1024 + off) =
        *(const uint4*)(Whh + ((long)((lr >> 4) << 10) + f0 + (lr & 15)) * 1024 + off);
  }
  float bhr = 0.f, bhz = 0.f, bhn = 0.f, hp = 0.f;   // gate lanes: tid<32
  if (tid < 32) {
    int ff = tid & 15;
    bhr = b_hh[f0 + ff]; bhz = b_hh[1024 + f0 + ff]; bhn = b_hh[2048 + f0 + ff];
  }
  __syncthreads();

  const int w = tid >> 6, l = tid & 63;
  const int b = w >> 2, q = w & 3;

  for (int t = 0; t < 1024; t++) {
    // prefetch x-gates (independent of h; in flight during the poll)
    float xr = 0.f, xz = 0.f, xn = 0.f;
    if (tid < 32) {
      int bb = tid >> 4, ff = tid & 15;
      const float* xb = xproj + (long)((bb << 10) + t) * 3072 + f0 + ff;
      xr = xb[0]; xz = xb[1024]; xn = xb[2048];
    }
    // poll tagged h_t: lane l needs cols {8l..8l+7} u {512+8l..+7} (8 u64)
    const u64* hb = (const u64*)hbuf + ((t & 1) << 10) + (b << 9);
    const unsigned tg = (unsigned)t;
    u64 d0, d1, d2, d3, e0, e1, e2, e3;
    for (;;) {
      d0 = __hip_atomic_load(hb + (l << 2),       __ATOMIC_RELAXED, __HIP_MEMORY_SCOPE_AGENT);
      d1 = __hip_atomic_load(hb + (l << 2) + 1,   __ATOMIC_RELAXED, __HIP_MEMORY_SCOPE_AGENT);
      d2 = __hip_atomic_load(hb + (l << 2) + 2,   __ATOMIC_RELAXED, __HIP_MEMORY_SCOPE_AGENT);
      d3 = __hip_atomic_load(hb + (l << 2) + 3,   __ATOMIC_RELAXED, __HIP_MEMORY_SCOPE_AGENT);
      e0 = __hip_atomic_load(hb + 256 + (l << 2),     __ATOMIC_RELAXED, __HIP_MEMORY_SCOPE_AGENT);
      e1 = __hip_atomic_load(hb + 256 + (l << 2) + 1, __ATOMIC_RELAXED, __HIP_MEMORY_SCOPE_AGENT);
      e2 = __hip_atomic_load(hb + 256 + (l << 2) + 2, __ATOMIC_RELAXED, __HIP_MEMORY_SCOPE_AGENT);
      e3 = __hip_atomic_load(hb + 256 + (l << 2) + 3, __ATOMIC_RELAXED, __HIP_MEMORY_SCOPE_AGENT);
      bool ok = (((unsigned)d0 >> 16) >= tg) & ((unsigned)(d0 >> 48) >= tg)
              & (((unsigned)d1 >> 16) >= tg) & ((unsigned)(d1 >> 48) >= tg)
              & (((unsigned)d2 >> 16) >= tg) & ((unsigned)(d2 >> 48) >= tg)
              & (((unsigned)d3 >> 16) >= tg) & ((unsigned)(d3 >> 48) >= tg)
              & (((unsigned)e0 >> 16) >= tg) & ((unsigned)(e0 >> 48) >= tg)
              & (((unsigned)e1 >> 16) >= tg) & ((unsigned)(e1 >> 48) >= tg)
              & (((unsigned)e2 >> 16) >= tg) & ((unsigned)(e2 >> 48) >= tg)
              & (((unsigned)e3 >> 16) >= tg) & ((unsigned)(e3 >> 48) >= tg);
      if (ok) break;
      __builtin_amdgcn_s_sleep(1);
    }
    float hA[8], hB[8];
    hA[0]=bflo((unsigned)d0); hA[1]=bflo((unsigned)(d0 >> 32));
    hA[2]=bflo((unsigned)d1); hA[3]=bflo((unsigned)(d1 >> 32));
    hA[4]=bflo((unsigned)d2); hA[5]=bflo((unsigned)(d2 >> 32));
    hA[6]=bflo((unsigned)d3); hA[7]=bflo((unsigned)(d3 >> 32));
    hB[0]=bflo((unsigned)e0); hB[1]=bflo((unsigned)(e0 >> 32));
    hB[2]=bflo((unsigned)e1); hB[3]=bflo((unsigned)(e1 >> 32));
    hB[4]=bflo((unsigned)e2); hB[5]=bflo((unsigned)(e2 >> 32));
    hB[6]=bflo((unsigned)e3); hB[7]=bflo((unsigned)(e3 >> 32));
    // 12 full-wave row-dots; each ds_read_b128 is 1KB wave-contiguous
#pragma unroll
    for (int r = 0; r < 12; r++) {
      int lr = q * 12 + r;
      uint4 w0 = *(const uint4*)(lW + lr * 1024 + (l << 3));
      uint4 w1 = *(const uint4*)(lW + lr * 1024 + 512 + (l << 3));
      float s = hA[0]*bflo(w0.x) + hA[1]*bfhi(w0.x)
              + hA[2]*bflo(w0.y) + hA[3]*bfhi(w0.y)
              + hA[4]*bflo(w0.z) + hA[5]*bfhi(w0.z)
              + hA[6]*bflo(w0.w) + hA[7]*bfhi(w0.w)
              + hB[0]*bflo(w1.x) + hB[1]*bfhi(w1.x)
              + hB[2]*bflo(w1.y) + hB[3]*bfhi(w1.y)
              + hB[4]*bflo(w1.z) + hB[5]*bfhi(w1.z)
              + hB[6]*bflo(w1.w) + hB[7]*bfhi(w1.w);
      s += __shfl_down(s, 32, 64);
      s += __shfl_down(s, 16, 64);
      s += __shfl_down(s, 8, 64);
      s += __shfl_down(s, 4, 64);
      s += __shfl_down(s, 2, 64);
      s += __shfl_down(s, 1, 64);
      if (l == 0) hgs[b][lr] = s;
    }
    __syncthreads();
    if (tid < 32) {
      int bb = tid >> 4, ff = tid & 15, f = f0 + ff;
      float rr = 1.f / (1.f + expf(-(xr + hgs[bb][ff] + bhr)));
      float zz = 1.f / (1.f + expf(-(xz + hgs[bb][16 + ff] + bhz)));
      float nn = tanhf(xn + rr * (hgs[bb][32 + ff] + bhn));
      float hnew = (1.f - zz) * nn + zz * hp;
      hp = hnew;
      states[(long)((bb << 10) + t) * 1024 + f] = hnew;
      unsigned word = ((unsigned)(t + 1) << 16) | (unsigned)f2bf(hnew);
      __hip_atomic_store(hbuf + (((t + 1) & 1) << 11) + (bb << 10) + f, word,
                         __ATOMIC_RELAXED, __HIP_MEMORY_SCOPE_AGENT);
    }
    // no barrier: next iteration's poll provides all cross-WG ordering;
    // hgs reuse is safe because any WG reaching step t+1's dots must have
    // observed full h_{t+1}, which requires THIS WG's gate lanes to have
    // read hgs (step t) and published.
  }
}

// ---------------- mixed + RMSnorm + gate -------------------------------------
__global__ __launch_bounds__(256) void mix_kernel(const float* __restrict__ states,
                                                  const float* __restrict__ inres,
                                                  const float* __restrict__ gate_W,
                                                  const float* __restrict__ gate_b,
                                                  const float* __restrict__ rlam,
                                                  const float* __restrict__ ilam,
                                                  const float* __restrict__ mscale,
                                                  u16* __restrict__ mixed_bf,
                                                  float* __restrict__ gate6) {
  const int row = blockIdx.x, tid = threadIdx.x, w = tid >> 6, l = tid & 63;
  __shared__ float red[16];
  float rl = rlam[0], il = ilam[0];
  const float* sr = states + (long)row * 1024;
  const float* ir = inres + (long)row * 1024;
  float m[4]; float ss = 0.f;
#pragma unroll
  for (int u = 0; u < 4; u++) {
    int h = (u << 8) + tid;
    m[u] = rl * sr[h] + il * ir[h];
    ss += m[u] * m[u];
  }
#pragma unroll
  for (int off = 32; off > 0; off >>= 1) ss += __shfl_down(ss, off, 64);
  if (l == 0) red[w] = ss;
  __syncthreads();
  float tot = red[0] + red[1] + red[2] + red[3];
  float scale = rsqrtf(tot * (1.f / 1024.f) + 1.1920929e-07f);
  float gd = 0.f;
#pragma unroll
  for (int u = 0; u < 4; u++) {
    int h = (u << 8) + tid;
    float v = m[u] * scale;
    mixed_bf[(long)row * 1024 + h] = f2bf(v);
    gd += v * gate_W[h];
  }
#pragma unroll
  for (int off = 32; off > 0; off >>= 1) gd += __shfl_down(gd, off, 64);
  if (l == 0) red[8 + w] = gd;
  __syncthreads();
  if (tid == 0) {
    float gsum = red[8] + red[9] + red[10] + red[11] + gate_b[0];
    gate6[row] = (1.f / (1.f + expf(-gsum))) * mscale[0];
  }
}

// ---------------- strictly-causal softmax attention -> gated -----------------
__global__ __launch_bounds__(256) void attn_kernel(const float* __restrict__ q,
                                                   const float* __restrict__ k,
                                                   const float* __restrict__ gate6,
                                                   float* __restrict__ gated) {
  const int bi = blockIdx.x; const int b = bi >> 10, i = bi & 1023;
  if (i == 0) return;
  const int tid = threadIdx.x, w = tid >> 6, l = tid & 63;
  __shared__ float sc[1024];
  __shared__ float red[16];
  const float4 qv = *(const float4*)(q + (long)bi * 256 + (l << 2));
  for (int j = w; j < i; j += 4) {
    float4 kv = *(const float4*)(k + ((long)(b << 10) + j) * 256 + (l << 2));
    float s = qv.x * kv.x + qv.y * kv.y + qv.z * kv.z + qv.w * kv.w;
#pragma unroll
    for (int off = 32; off > 0; off >>= 1) s += __shfl_down(s, off, 64);
    if (l == 0) sc[j] = s * 0.0625f;       // 1/sqrt(256)
  }
  __syncthreads();
  float mx = -3.0e38f;
  for (int j = tid; j < i; j += 256) mx = fmaxf(mx, sc[j]);
#pragma unroll
  for (int off = 32; off > 0; off >>= 1) mx = fmaxf(mx, __shfl_down(mx, off, 64));
  if (l == 0) red[w] = mx;
  __syncthreads();
  mx = fmaxf(fmaxf(red[0], red[1]), fmaxf(red[2], red[3]));
  float sum = 0.f;
  for (int j = tid; j < i; j += 256) { float e = expf(sc[j] - mx); sc[j] = e; sum += e; }
#pragma unroll
  for (int off = 32; off > 0; off >>= 1) sum += __shfl_down(sum, off, 64);
  if (l == 0) red[8 + w] = sum;
  __syncthreads();
  sum = red[8] + red[9] + red[10] + red[11];
  float invs = gate6[bi] / sum;
  float* grow = gated + (long)bi * 1024;
  for (int j = tid; j < i; j += 256) grow[j] = sc[j] * invs;
}

// ---------------- scatter-add into logits ------------------------------------
__global__ __launch_bounds__(256) void scatter_kernel(const int* __restrict__ ids,
                                                      const float* __restrict__ gated,
                                                      float* __restrict__ out) {
  const int bi = blockIdx.x; const int b = bi >> 10, i = bi & 1023;
  const float* g = gated + (long)bi * 1024;
  float* o = out + (long)bi * 32000;
  const int* idr = ids + (b << 10);
  for (int j = threadIdx.x; j < i; j += 256)
    atomicAdd(o + idr[j], g[j]);
}

extern "C" void kernel_launch(void* const* d_in, const int* in_sizes, int n_in,
                              void* d_out, int out_size, void* d_ws, size_t ws_size,
                              hipStream_t stream) {
  const int*   ids      = (const int*)  d_in[0];
  const float* emb_W    = (const float*)d_in[1];
  const float* W_ih     = (const float*)d_in[2];
  const float* W_hh     = (const float*)d_in[3];
  const float* b_ih     = (const float*)d_in[4];
  const float* b_hh     = (const float*)d_in[5];
  const float* in_res_W = (const float*)d_in[6];
  const float* q_W      = (const float*)d_in[7];
  const float* q_b      = (const float*)d_in[8];
  const float* k_W      = (const float*)d_in[9];
  const float* k_b      = (const float*)d_in[10];
  const float* gate_W   = (const float*)d_in[11];
  const float* gate_b   = (const float*)d_in[12];
  const float* h2e_W    = (const float*)d_in[13];
  const float* h2e_b    = (const float*)d_in[14];
  const float* out_bias = (const float*)d_in[15];
  const float* mscale   = (const float*)d_in[16];
  const float* rlam     = (const float*)d_in[17];
  const float* ilam     = (const float*)d_in[18];
  float* out = (float*)d_out;

  char* p = (char*)d_ws;
  auto alloc = [&](size_t b) { char* r = p; p += (b + 255) & ~(size_t)255; return (void*)r; };
  u16*   emb_bf   = (u16*)  alloc((size_t)2048 * 512 * 2);
  u16*   Wih_bf   = (u16*)  alloc((size_t)3072 * 512 * 2);
  u16*   inresW_bf= (u16*)  alloc((size_t)1024 * 512 * 2);
  u16*   Whh_bf   = (u16*)  alloc((size_t)3072 * 1024 * 2);
  u16*   h2e_bf   = (u16*)  alloc((size_t)512 * 1024 * 2);
  u16*   qW_bf    = (u16*)  alloc((size_t)256 * 1024 * 2);
  u16*   kW_bf    = (u16*)  alloc((size_t)256 * 1024 * 2);
  u16*   embW_bf  = (u16*)  alloc((size_t)32000 * 512 * 2);
  float* xproj    = (float*)alloc((size_t)2048 * 3072 * 4);
  float* inres    = (float*)alloc((size_t)2048 * 1024 * 4);
  float* states   = (float*)alloc((size_t)2048 * 1024 * 4);
  u16*   mixed_bf = (u16*)  alloc((size_t)2048 * 1024 * 2);
  float* tbuf     = (float*)alloc((size_t)2048 * 512 * 4);
  u16*   t_bf     = (u16*)  alloc((size_t)2048 * 512 * 2);
  float* qbuf     = (float*)alloc((size_t)2048 * 256 * 4);
  float* kbuf     = (float*)alloc((size_t)2048 * 256 * 4);
  float* gated    = (float*)alloc((size_t)2048 * 1024 * 4);
  float* gate6    = (float*)alloc((size_t)2048 * 4);
  unsigned* hbuf  = (unsigned*)alloc((size_t)2 * 2 * 1024 * 4);

  hipMemsetAsync(hbuf, 0, 2 * 2 * 1024 * 4, stream);

  // weight / input conversions to bf16
  f2bf_kernel<<<1024, 256, 0, stream>>>(W_ih, Wih_bf, 3072 * 512);
  f2bf_kernel<<<512, 256, 0, stream>>>(in_res_W, inresW_bf, 1024 * 512);
  f2bf_kernel<<<1024, 256, 0, stream>>>(W_hh, Whh_bf, 3072 * 1024);
  f2bf_kernel<<<512, 256, 0, stream>>>(h2e_W, h2e_bf, 512 * 1024);
  f2bf_kernel<<<256, 256, 0, stream>>>(q_W, qW_bf, 256 * 1024);
  f2bf_kernel<<<256, 256, 0, stream>>>(k_W, kW_bf, 256 * 1024);
  f2bf_kernel<<<2048, 256, 0, stream>>>(emb_W, embW_bf, 32000 * 512);
  gather_kernel<<<2048, 256, 0, stream>>>(ids, emb_W, emb_bf);

  // x_proj = emb @ W_ih.T + b_ih ;  inres = emb @ in_res_W.T
  gemm_bt<<<dim3(24, 16), 256, 0, stream>>>(emb_bf, Wih_bf, xproj, b_ih, 2048, 3072, 512);
  gemm_bt<<<dim3(8, 16), 256, 0, stream>>>(emb_bf, inresW_bf, inres, nullptr, 2048, 1024, 512);

  // sequential GRU over S=1024 (barrier-free tagged-h pipeline, 64 WGs)
  gru_kernel<<<64, 512, 0, stream>>>(Whh_bf, b_hh, xproj, hbuf, states);

  // mixed + RMS + gate
  mix_kernel<<<2048, 256, 0, stream>>>(states, inres, gate_W, gate_b, rlam, ilam, mscale,
                                       mixed_bf, gate6);

  // q, k, t projections
  gemm_bt<<<dim3(2, 16), 256, 0, stream>>>(mixed_bf, qW_bf, qbuf, q_b, 2048, 256, 1024);
  gemm_bt<<<dim3(2, 16), 256, 0, stream>>>(mixed_bf, kW_bf, kbuf, k_b, 2048, 256, 1024);
  gemm_bt<<<dim3(4, 16), 256, 0, stream>>>(mixed_bf, h2e_bf, tbuf, h2e_b, 2048, 512, 1024);
  f2bf_kernel<<<512, 256, 0, stream>>>(tbuf, t_bf, 2048 * 512);

  // attention -> gated
  attn_kernel<<<2048, 256, 0, stream>>>(qbuf, kbuf, gate6, gated);

  // base logits (big GEMM, writes all of d_out) then scatter-add
  gemm_bt<<<dim3(250, 16), 256, 0, stream>>>(t_bf, embW_bf, out, out_bias, 2048, 32000, 512);
  scatter_kernel<<<2048, 256, 0, stream>>>(ids, gated, out);
}

// Round 6
// 5978.718 us; speedup vs baseline: 1.3377x; 1.2246x over previous
//
#include <hip/hip_runtime.h>
#include <math.h>

typedef unsigned short u16;
typedef unsigned long long u64;
typedef __bf16 bf16x8 __attribute__((ext_vector_type(8)));
typedef float f32x4 __attribute__((ext_vector_type(4)));

#define AS1(p) ((const __attribute__((address_space(1))) void*)(p))
#define AS3(p) ((__attribute__((address_space(3))) void*)(p))

__device__ __forceinline__ u16 f2bf(float x) {
  unsigned u = __float_as_uint(x);
  u = u + 0x7fffu + ((u >> 16) & 1u);
  return (u16)(u >> 16);
}
__device__ __forceinline__ float bflo(unsigned x){ return __uint_as_float(x << 16); }
__device__ __forceinline__ float bfhi(unsigned x){ return __uint_as_float(x & 0xffff0000u); }

// ---------------- generic f32 -> bf16 ----------------
__global__ __launch_bounds__(256) void f2bf_kernel(const float* __restrict__ in,
                                                   u16* __restrict__ out, int n) {
  int i = blockIdx.x * 256 + threadIdx.x;
  int stride = gridDim.x * 256;
  for (; i < n; i += stride) out[i] = f2bf(in[i]);
}

// ---------------- embedding gather -> bf16 ----------------
__global__ __launch_bounds__(256) void gather_kernel(const int* __restrict__ ids,
                                                     const float* __restrict__ embW,
                                                     u16* __restrict__ out) {
  int row = blockIdx.x;                       // token index b*1024+s
  long base = (long)ids[row] << 9;            // *512
  long obase = (long)row << 9;
  for (int c = threadIdx.x; c < 512; c += 256) out[obase + c] = f2bf(embW[base + c]);
}

// ---------------- bf16 MFMA GEMM: C[M,N] = A[M,K] @ Bt[N,K]^T (+bias[N]) ------
__global__ __launch_bounds__(256) void gemm_bt(const u16* __restrict__ A,
                                               const u16* __restrict__ Bt,
                                               float* __restrict__ C,
                                               const float* __restrict__ bias,
                                               int M, int N, int K) {
  __shared__ __attribute__((aligned(16))) u16 lA[128 * 32];
  __shared__ __attribute__((aligned(16))) u16 lB[128 * 32];
  const int tid = threadIdx.x;
  const int w = tid >> 6, l = tid & 63;
  const int bn = blockIdx.x, bm = blockIdx.y;
  const int frow = l & 15, fq = l >> 4;
  const int wm = (w >> 1) * 64, wn = (w & 1) * 64;
  f32x4 acc[16];
#pragma unroll
  for (int i = 0; i < 16; i++) acc[i] = (f32x4){0.f, 0.f, 0.f, 0.f};

  const long a0 = (long)bm * 128 * K;
  const long b0 = (long)bn * 128 * K;
  for (int k0 = 0; k0 < K; k0 += 32) {
#pragma unroll
    for (int p = 0; p < 2; p++) {
      int q = (p * 4 + w) * 64 + l;          // chunk 0..511
      int r = q >> 2, c = (q & 3) << 3;      // row, col-offset (ushorts)
      __builtin_amdgcn_global_load_lds(AS1(A + a0 + (long)r * K + k0 + c),
                                       AS3(&lA[(p * 4 + w) * 512]), 16, 0, 0);
      __builtin_amdgcn_global_load_lds(AS1(Bt + b0 + (long)r * K + k0 + c),
                                       AS3(&lB[(p * 4 + w) * 512]), 16, 0, 0);
    }
    __syncthreads();
    bf16x8 af[4], bfv[4];
#pragma unroll
    for (int i = 0; i < 4; i++) af[i]  = *(const bf16x8*)&lA[(wm + i * 16 + frow) * 32 + fq * 8];
#pragma unroll
    for (int j = 0; j < 4; j++) bfv[j] = *(const bf16x8*)&lB[(wn + j * 16 + frow) * 32 + fq * 8];
#pragma unroll
    for (int i = 0; i < 4; i++)
#pragma unroll
      for (int j = 0; j < 4; j++)
        acc[i * 4 + j] = __builtin_amdgcn_mfma_f32_16x16x32_bf16(af[i], bfv[j], acc[i * 4 + j], 0, 0, 0);
    __syncthreads();
  }
#pragma unroll
  for (int i = 0; i < 4; i++) {
    int row = bm * 128 + wm + i * 16 + fq * 4;
#pragma unroll
    for (int j = 0; j < 4; j++) {
      int col = bn * 128 + wn + j * 16 + frow;
      float bv = bias ? bias[col] : 0.f;
#pragma unroll
      for (int r = 0; r < 4; r++)
        C[(long)(row + r) * N + col] = acc[i * 4 + j][r] + bv;
    }
  }
}

// ---------------- GRU: persistent grid, flag-in-data, FEW POLLERS ------------
// Empirical law from R2/R3/R5 counters: agent-scope poll cost scales with the
// number of polling lanes (64 pollers -> ~2.7us/step sync; 16K-32K pollers ->
// ~6us/step), because agent loads bypass the per-XCD L2s and congest the IF$
// coherence point that the producers' publish stores must also traverse.
//
// This version keeps R5's flag-in-data scheme (tag rides in the same u32 as
// the bf16 h value -> detect IS the data load, no separate flag RTT, no RMW,
// no s_waitcnt on the publish path) but polls with only TWO WAVES per WG:
// wave 0 polls batch 0's tagged h-half, wave 4 polls batch 1's. Each polling
// lane loads 8 coalesced u64 (512B/instr across the wave; each 128B line is
// polled by exactly ONE lane per WG = 64 requests/line/round chip-wide, the
// R2 population). After tags pass, the poll wave strips tags and stages h
// into LDS; the other 6 waves wait at __syncthreads (no global traffic).
//
// Parity double-buffer safety (unchanged from R5): a producer writes parity-p
// tag t+1 only after its step-t poll observed all of h_t, which required all
// WGs' wave-0/4 to have completed their step t-1 poll loads of parity p; the
// poll loads are the only readers of hbuf, so overwrite is safe. Tags are
// monotone; check is (tag >= t). hbuf zeroed each launch -> tag 0 == step-0.
//
// 64 WGs x 512 thr (~103KB LDS -> 1 WG/CU, trivially co-resident).
// WG g owns feats f0=16g..+15 (48 W_hh rows x 2 batches = 96 row-dots).
// Wave w: batch b=w>>2, rows (w&3)*12..+11; conflict-free full-wave dots
// (2x wave-contiguous ds_read_b128 per row from lW, 2 from lh).
__global__ __launch_bounds__(512) void gru_kernel(const u16* __restrict__ Whh,
                                                  const float* __restrict__ b_hh,
                                                  const float* __restrict__ xproj,
                                                  unsigned* __restrict__ hbuf, // [2][2][1024] u32 tagged
                                                  float* __restrict__ states) { // [2][1024][1024]
  __shared__ __attribute__((aligned(16))) u16 lW[48 * 1024];
  __shared__ __attribute__((aligned(16))) u16 lh[2 * 1024];
  __shared__ float hgs[2][48];
  const int g = blockIdx.x;
  const int tid = threadIdx.x;
  const int f0 = g * 16;
  // stage 48 W_hh rows: lr = gate*16 + ff  ->  global row gate*1024 + f0 + ff
  for (int c = tid; c < 6144; c += 512) {            // 6144 chunks of 8 ushorts
    int lr = c >> 7, off = (c & 127) << 3;
    *(uint4*)(lW + lr * 1024 + off) =
        *(const uint4*)(Whh + ((long)((lr >> 4) << 10) + f0 + (lr & 15)) * 1024 + off);
  }
  float bhr = 0.f, bhz = 0.f, bhn = 0.f, hp = 0.f;   // gate lanes: tid<32
  if (tid < 32) {
    int ff = tid & 15;
    bhr = b_hh[f0 + ff]; bhz = b_hh[1024 + f0 + ff]; bhn = b_hh[2048 + f0 + ff];
  }
  __syncthreads();

  const int w = tid >> 6, l = tid & 63;
  const int b = w >> 2, q = w & 3;
  unsigned* lh32 = (unsigned*)lh;
  const uint4* lh4 = (const uint4*)lh;

  for (int t = 0; t < 1024; t++) {
    // prefetch x-gates (independent of h; in flight during the poll)
    float xr = 0.f, xz = 0.f, xn = 0.f;
    if (tid < 32) {
      int bb = tid >> 4, ff = tid & 15;
      const float* xb = xproj + (long)((bb << 10) + t) * 3072 + f0 + ff;
      xr = xb[0]; xz = xb[1024]; xn = xb[2048];
    }
    // waves 0 (b=0) and 4 (b=1) poll their batch's tagged h-half: 8 u64/lane,
    // each load instruction spans 512B contiguous across the wave.
    if (q == 0) {
      const u64* hb = (const u64*)hbuf + ((t & 1) << 10) + (b << 9);
      const unsigned tg = (unsigned)t;
      u64 v[8];
      for (;;) {
        bool ok = true;
#pragma unroll
        for (int k = 0; k < 8; k++)
          v[k] = __hip_atomic_load(hb + (k << 6) + l, __ATOMIC_RELAXED, __HIP_MEMORY_SCOPE_AGENT);
#pragma unroll
        for (int k = 0; k < 8; k++)
          ok &= (((unsigned)v[k] >> 16) >= tg) & ((unsigned)(v[k] >> 48) >= tg);
        if (__all(ok)) break;
        __builtin_amdgcn_s_sleep(1);
      }
      // strip tags, stage h into LDS: u32 j holds cols 2j,2j+1 (bf16 pair)
#pragma unroll
      for (int k = 0; k < 8; k++)
        lh32[(b << 9) + (k << 6) + l] =
            ((unsigned)v[k] & 0xffffu) | ((unsigned)(v[k] >> 32) << 16);
    }
    __syncthreads();
    // read h from LDS: cols 8l..8l+7 and 512+8l..+7 (wave-contiguous 1KB)
    uint4 X = lh4[(b << 7) + l];
    uint4 Y = lh4[(b << 7) + 64 + l];
    float hA[8], hB[8];
    hA[0]=bflo(X.x); hA[1]=bfhi(X.x); hA[2]=bflo(X.y); hA[3]=bfhi(X.y);
    hA[4]=bflo(X.z); hA[5]=bfhi(X.z); hA[6]=bflo(X.w); hA[7]=bfhi(X.w);
    hB[0]=bflo(Y.x); hB[1]=bfhi(Y.x); hB[2]=bflo(Y.y); hB[3]=bfhi(Y.y);
    hB[4]=bflo(Y.z); hB[5]=bfhi(Y.z); hB[6]=bflo(Y.w); hB[7]=bfhi(Y.w);
    // 12 full-wave row-dots; each ds_read_b128 is 1KB wave-contiguous
#pragma unroll
    for (int r = 0; r < 12; r++) {
      int lr = q * 12 + r;
      uint4 w0 = *(const uint4*)(lW + lr * 1024 + (l << 3));
      uint4 w1 = *(const uint4*)(lW + lr * 1024 + 512 + (l << 3));
      float s = hA[0]*bflo(w0.x) + hA[1]*bfhi(w0.x)
              + hA[2]*bflo(w0.y) + hA[3]*bfhi(w0.y)
              + hA[4]*bflo(w0.z) + hA[5]*bfhi(w0.z)
              + hA[6]*bflo(w0.w) + hA[7]*bfhi(w0.w)
              + hB[0]*bflo(w1.x) + hB[1]*bfhi(w1.x)
              + hB[2]*bflo(w1.y) + hB[3]*bfhi(w1.y)
              + hB[4]*bflo(w1.z) + hB[5]*bfhi(w1.z)
              + hB[6]*bflo(w1.w) + hB[7]*bfhi(w1.w);
      s += __shfl_down(s, 32, 64);
      s += __shfl_down(s, 16, 64);
      s += __shfl_down(s, 8, 64);
      s += __shfl_down(s, 4, 64);
      s += __shfl_down(s, 2, 64);
      s += __shfl_down(s, 1, 64);
      if (l == 0) hgs[b][lr] = s;
    }
    __syncthreads();
    if (tid < 32) {
      int bb = tid >> 4, ff = tid & 15, f = f0 + ff;
      float rr = 1.f / (1.f + expf(-(xr + hgs[bb][ff] + bhr)));
      float zz = 1.f / (1.f + expf(-(xz + hgs[bb][16 + ff] + bhz)));
      float nn = tanhf(xn + rr * (hgs[bb][32 + ff] + bhn));
      float hnew = (1.f - zz) * nn + zz * hp;
      hp = hnew;
      states[(long)((bb << 10) + t) * 1024 + f] = hnew;
      unsigned word = ((unsigned)(t + 1) << 16) | (unsigned)f2bf(hnew);
      __hip_atomic_store(hbuf + (((t + 1) & 1) << 11) + (bb << 10) + f, word,
                         __ATOMIC_RELAXED, __HIP_MEMORY_SCOPE_AGENT);
    }
    // no extra barrier: lh/hgs reuse is fenced by the two __syncthreads above
    // (all reads of lh(t)/hgs(t) complete before the second sync; wave 0/4
    // only overwrite lh after passing it).
  }
}

// ---------------- mixed + RMSnorm + gate -------------------------------------
__global__ __launch_bounds__(256) void mix_kernel(const float* __restrict__ states,
                                                  const float* __restrict__ inres,
                                                  const float* __restrict__ gate_W,
                                                  const float* __restrict__ gate_b,
                                                  const float* __restrict__ rlam,
                                                  const float* __restrict__ ilam,
                                                  const float* __restrict__ mscale,
                                                  u16* __restrict__ mixed_bf,
                                                  float* __restrict__ gate6) {
  const int row = blockIdx.x, tid = threadIdx.x, w = tid >> 6, l = tid & 63;
  __shared__ float red[16];
  float rl = rlam[0], il = ilam[0];
  const float* sr = states + (long)row * 1024;
  const float* ir = inres + (long)row * 1024;
  float m[4]; float ss = 0.f;
#pragma unroll
  for (int u = 0; u < 4; u++) {
    int h = (u << 8) + tid;
    m[u] = rl * sr[h] + il * ir[h];
    ss += m[u] * m[u];
  }
#pragma unroll
  for (int off = 32; off > 0; off >>= 1) ss += __shfl_down(ss, off, 64);
  if (l == 0) red[w] = ss;
  __syncthreads();
  float tot = red[0] + red[1] + red[2] + red[3];
  float scale = rsqrtf(tot * (1.f / 1024.f) + 1.1920929e-07f);
  float gd = 0.f;
#pragma unroll
  for (int u = 0; u < 4; u++) {
    int h = (u << 8) + tid;
    float v = m[u] * scale;
    mixed_bf[(long)row * 1024 + h] = f2bf(v);
    gd += v * gate_W[h];
  }
#pragma unroll
  for (int off = 32; off > 0; off >>= 1) gd += __shfl_down(gd, off, 64);
  if (l == 0) red[8 + w] = gd;
  __syncthreads();
  if (tid == 0) {
    float gsum = red[8] + red[9] + red[10] + red[11] + gate_b[0];
    gate6[row] = (1.f / (1.f + expf(-gsum))) * mscale[0];
  }
}

// ---------------- strictly-causal softmax attention -> gated -----------------
__global__ __launch_bounds__(256) void attn_kernel(const float* __restrict__ q,
                                                   const float* __restrict__ k,
                                                   const float* __restrict__ gate6,
                                                   float* __restrict__ gated) {
  const int bi = blockIdx.x; const int b = bi >> 10, i = bi & 1023;
  if (i == 0) return;
  const int tid = threadIdx.x, w = tid >> 6, l = tid & 63;
  __shared__ float sc[1024];
  __shared__ float red[16];
  const float4 qv = *(const float4*)(q + (long)bi * 256 + (l << 2));
  for (int j = w; j < i; j += 4) {
    float4 kv = *(const float4*)(k + ((long)(b << 10) + j) * 256 + (l << 2));
    float s = qv.x * kv.x + qv.y * kv.y + qv.z * kv.z + qv.w * kv.w;
#pragma unroll
    for (int off = 32; off > 0; off >>= 1) s += __shfl_down(s, off, 64);
    if (l == 0) sc[j] = s * 0.0625f;       // 1/sqrt(256)
  }
  __syncthreads();
  float mx = -3.0e38f;
  for (int j = tid; j < i; j += 256) mx = fmaxf(mx, sc[j]);
#pragma unroll
  for (int off = 32; off > 0; off >>= 1) mx = fmaxf(mx, __shfl_down(mx, off, 64));
  if (l == 0) red[w] = mx;
  __syncthreads();
  mx = fmaxf(fmaxf(red[0], red[1]), fmaxf(red[2], red[3]));
  float sum = 0.f;
  for (int j = tid; j < i; j += 256) { float e = expf(sc[j] - mx); sc[j] = e; sum += e; }
#pragma unroll
  for (int off = 32; off > 0; off >>= 1) sum += __shfl_down(sum, off, 64);
  if (l == 0) red[8 + w] = sum;
  __syncthreads();
  sum = red[8] + red[9] + red[10] + red[11];
  float invs = gate6[bi] / sum;
  float* grow = gated + (long)bi * 1024;
  for (int j = tid; j < i; j += 256) grow[j] = sc[j] * invs;
}

// ---------------- scatter-add into logits ------------------------------------
__global__ __launch_bounds__(256) void scatter_kernel(const int* __restrict__ ids,
                                                      const float* __restrict__ gated,
                                                      float* __restrict__ out) {
  const int bi = blockIdx.x; const int b = bi >> 10, i = bi & 1023;
  const float* g = gated + (long)bi * 1024;
  float* o = out + (long)bi * 32000;
  const int* idr = ids + (b << 10);
  for (int j = threadIdx.x; j < i; j += 256)
    atomicAdd(o + idr[j], g[j]);
}

extern "C" void kernel_launch(void* const* d_in, const int* in_sizes, int n_in,
                              void* d_out, int out_size, void* d_ws, size_t ws_size,
                              hipStream_t stream) {
  const int*   ids      = (const int*)  d_in[0];
  const float* emb_W    = (const float*)d_in[1];
  const float* W_ih     = (const float*)d_in[2];
  const float* W_hh     = (const float*)d_in[3];
  const float* b_ih     = (const float*)d_in[4];
  const float* b_hh     = (const float*)d_in[5];
  const float* in_res_W = (const float*)d_in[6];
  const float* q_W      = (const float*)d_in[7];
  const float* q_b      = (const float*)d_in[8];
  const float* k_W      = (const float*)d_in[9];
  const float* k_b      = (const float*)d_in[10];
  const float* gate_W   = (const float*)d_in[11];
  const float* gate_b   = (const float*)d_in[12];
  const float* h2e_W    = (const float*)d_in[13];
  const float* h2e_b    = (const float*)d_in[14];
  const float* out_bias = (const float*)d_in[15];
  const float* mscale   = (const float*)d_in[16];
  const float* rlam     = (const float*)d_in[17];
  const float* ilam     = (const float*)d_in[18];
  float* out = (float*)d_out;

  char* p = (char*)d_ws;
  auto alloc = [&](size_t b) { char* r = p; p += (b + 255) & ~(size_t)255; return (void*)r; };
  u16*   emb_bf   = (u16*)  alloc((size_t)2048 * 512 * 2);
  u16*   Wih_bf   = (u16*)  alloc((size_t)3072 * 512 * 2);
  u16*   inresW_bf= (u16*)  alloc((size_t)1024 * 512 * 2);
  u16*   Whh_bf   = (u16*)  alloc((size_t)3072 * 1024 * 2);
  u16*   h2e_bf   = (u16*)  alloc((size_t)512 * 1024 * 2);
  u16*   qW_bf    = (u16*)  alloc((size_t)256 * 1024 * 2);
  u16*   kW_bf    = (u16*)  alloc((size_t)256 * 1024 * 2);
  u16*   embW_bf  = (u16*)  alloc((size_t)32000 * 512 * 2);
  float* xproj    = (float*)alloc((size_t)2048 * 3072 * 4);
  float* inres    = (float*)alloc((size_t)2048 * 1024 * 4);
  float* states   = (float*)alloc((size_t)2048 * 1024 * 4);
  u16*   mixed_bf = (u16*)  alloc((size_t)2048 * 1024 * 2);
  float* tbuf     = (float*)alloc((size_t)2048 * 512 * 4);
  u16*   t_bf     = (u16*)  alloc((size_t)2048 * 512 * 2);
  float* qbuf     = (float*)alloc((size_t)2048 * 256 * 4);
  float* kbuf     = (float*)alloc((size_t)2048 * 256 * 4);
  float* gated    = (float*)alloc((size_t)2048 * 1024 * 4);
  float* gate6    = (float*)alloc((size_t)2048 * 4);
  unsigned* hbuf  = (unsigned*)alloc((size_t)2 * 2 * 1024 * 4);

  hipMemsetAsync(hbuf, 0, 2 * 2 * 1024 * 4, stream);

  // weight / input conversions to bf16
  f2bf_kernel<<<1024, 256, 0, stream>>>(W_ih, Wih_bf, 3072 * 512);
  f2bf_kernel<<<512, 256, 0, stream>>>(in_res_W, inresW_bf, 1024 * 512);
  f2bf_kernel<<<1024, 256, 0, stream>>>(W_hh, Whh_bf, 3072 * 1024);
  f2bf_kernel<<<512, 256, 0, stream>>>(h2e_W, h2e_bf, 512 * 1024);
  f2bf_kernel<<<256, 256, 0, stream>>>(q_W, qW_bf, 256 * 1024);
  f2bf_kernel<<<256, 256, 0, stream>>>(k_W, kW_bf, 256 * 1024);
  f2bf_kernel<<<2048, 256, 0, stream>>>(emb_W, embW_bf, 32000 * 512);
  gather_kernel<<<2048, 256, 0, stream>>>(ids, emb_W, emb_bf);

  // x_proj = emb @ W_ih.T + b_ih ;  inres = emb @ in_res_W.T
  gemm_bt<<<dim3(24, 16), 256, 0, stream>>>(emb_bf, Wih_bf, xproj, b_ih, 2048, 3072, 512);
  gemm_bt<<<dim3(8, 16), 256, 0, stream>>>(emb_bf, inresW_bf, inres, nullptr, 2048, 1024, 512);

  // sequential GRU over S=1024 (flag-in-data, 2 poll waves per WG, 64 WGs)
  gru_kernel<<<64, 512, 0, stream>>>(Whh_bf, b_hh, xproj, hbuf, states);

  // mixed + RMS + gate
  mix_kernel<<<2048, 256, 0, stream>>>(states, inres, gate_W, gate_b, rlam, ilam, mscale,
                                       mixed_bf, gate6);

  // q, k, t projections
  gemm_bt<<<dim3(2, 16), 256, 0, stream>>>(mixed_bf, qW_bf, qbuf, q_b, 2048, 256, 1024);
  gemm_bt<<<dim3(2, 16), 256, 0, stream>>>(mixed_bf, kW_bf, kbuf, k_b, 2048, 256, 1024);
  gemm_bt<<<dim3(4, 16), 256, 0, stream>>>(mixed_bf, h2e_bf, tbuf, h2e_b, 2048, 512, 1024);
  f2bf_kernel<<<512, 256, 0, stream>>>(tbuf, t_bf, 2048 * 512);

  // attention -> gated
  attn_kernel<<<2048, 256, 0, stream>>>(qbuf, kbuf, gate6, gated);

  // base logits (big GEMM, writes all of d_out) then scatter-add
  gemm_bt<<<dim3(250, 16), 256, 0, stream>>>(t_bf, embW_bf, out, out_bias, 2048, 32000, 512);
  scatter_kernel<<<2048, 256, 0, stream>>>(ids, gated, out);
}

// Round 8
// 2739.263 us; speedup vs baseline: 2.9197x; 2.1826x over previous
//
#include <hip/hip_runtime.h>
#include <math.h>

typedef unsigned short u16;
typedef unsigned long long u64;
typedef __bf16 bf16x8 __attribute__((ext_vector_type(8)));
typedef float f32x4 __attribute__((ext_vector_type(4)));

#define AS1(p) ((const __attribute__((address_space(1))) void*)(p))
#define AS3(p) ((__attribute__((address_space(3))) void*)(p))

__device__ __forceinline__ u16 f2bf(float x) {
  unsigned u = __float_as_uint(x);
  u = u + 0x7fffu + ((u >> 16) & 1u);
  return (u16)(u >> 16);
}
__device__ __forceinline__ float bflo(unsigned x){ return __uint_as_float(x << 16); }
__device__ __forceinline__ float bfhi(unsigned x){ return __uint_as_float(x & 0xffff0000u); }

// ---------------- generic f32 -> bf16 ----------------
__global__ __launch_bounds__(256) void f2bf_kernel(const float* __restrict__ in,
                                                   u16* __restrict__ out, int n) {
  int i = blockIdx.x * 256 + threadIdx.x;
  int stride = gridDim.x * 256;
  for (; i < n; i += stride) out[i] = f2bf(in[i]);
}

// ---------------- embedding gather -> bf16 ----------------
__global__ __launch_bounds__(256) void gather_kernel(const int* __restrict__ ids,
                                                     const float* __restrict__ embW,
                                                     u16* __restrict__ out) {
  int row = blockIdx.x;                       // token index b*1024+s
  long base = (long)ids[row] << 9;            // *512
  long obase = (long)row << 9;
  for (int c = threadIdx.x; c < 512; c += 256) out[obase + c] = f2bf(embW[base + c]);
}

// ---------------- bf16 MFMA GEMM: C[M,N] = A[M,K] @ Bt[N,K]^T (+bias[N]) ------
__global__ __launch_bounds__(256) void gemm_bt(const u16* __restrict__ A,
                                               const u16* __restrict__ Bt,
                                               float* __restrict__ C,
                                               const float* __restrict__ bias,
                                               int M, int N, int K) {
  __shared__ __attribute__((aligned(16))) u16 lA[128 * 32];
  __shared__ __attribute__((aligned(16))) u16 lB[128 * 32];
  const int tid = threadIdx.x;
  const int w = tid >> 6, l = tid & 63;
  const int bn = blockIdx.x, bm = blockIdx.y;
  const int frow = l & 15, fq = l >> 4;
  const int wm = (w >> 1) * 64, wn = (w & 1) * 64;
  f32x4 acc[16];
#pragma unroll
  for (int i = 0; i < 16; i++) acc[i] = (f32x4){0.f, 0.f, 0.f, 0.f};

  const long a0 = (long)bm * 128 * K;
  const long b0 = (long)bn * 128 * K;
  for (int k0 = 0; k0 < K; k0 += 32) {
#pragma unroll
    for (int p = 0; p < 2; p++) {
      int q = (p * 4 + w) * 64 + l;          // chunk 0..511
      int r = q >> 2, c = (q & 3) << 3;      // row, col-offset (ushorts)
      __builtin_amdgcn_global_load_lds(AS1(A + a0 + (long)r * K + k0 + c),
                                       AS3(&lA[(p * 4 + w) * 512]), 16, 0, 0);
      __builtin_amdgcn_global_load_lds(AS1(Bt + b0 + (long)r * K + k0 + c),
                                       AS3(&lB[(p * 4 + w) * 512]), 16, 0, 0);
    }
    __syncthreads();
    bf16x8 af[4], bfv[4];
#pragma unroll
    for (int i = 0; i < 4; i++) af[i]  = *(const bf16x8*)&lA[(wm + i * 16 + frow) * 32 + fq * 8];
#pragma unroll
    for (int j = 0; j < 4; j++) bfv[j] = *(const bf16x8*)&lB[(wn + j * 16 + frow) * 32 + fq * 8];
#pragma unroll
    for (int i = 0; i < 4; i++)
#pragma unroll
      for (int j = 0; j < 4; j++)
        acc[i * 4 + j] = __builtin_amdgcn_mfma_f32_16x16x32_bf16(af[i], bfv[j], acc[i * 4 + j], 0, 0, 0);
    __syncthreads();
  }
#pragma unroll
  for (int i = 0; i < 4; i++) {
    int row = bm * 128 + wm + i * 16 + fq * 4;
#pragma unroll
    for (int j = 0; j < 4; j++) {
      int col = bn * 128 + wn + j * 16 + frow;
      float bv = bias ? bias[col] : 0.f;
#pragma unroll
      for (int r = 0; r < 4; r++)
        C[(long)(row + r) * N + col] = acc[i * 4 + j][r] + bv;
    }
  }
}

// ---------------- GRU: flag-in-data sync + MFMA dot core ---------------------
// R6 decomposition: step = ~2.7us IF$ sync constant + ~2.35us DS-pipe time
// (576 shfl + 192 ds_read_b128 per CU per step -- invisible to our SQ counters
// but arithmetic from m134 rates matches the R2/R5/R6 deltas). This version
// eliminates the DS term:
//  - HG^T[48,2] = W[48,1024] @ h^T[1024,2] is computed with MFMA 16x16x32
//    (both batches packed into the N dimension of one MFMA).
//  - W A-fragments are PERSISTENT IN VGPRS (16 frags x 4 VGPR = 64 VGPR per
//    compute wave, loaded once; W never touches LDS -> zero steady-state W
//    traffic).
//  - The 576 shfls/CU vanish: MFMA's C layout delivers the 48 gate sums
//    directly (col=lane&15=batch, row=(lane>>4)*4+reg).
//  - h staged once per step into 4KB LDS by the two poll waves (R6's proven
//    tagged-word protocol, unchanged); B-frags read from it with 2-way-free
//    bank behavior (96 ds_read_b128/CU/step total).
// Wave roles (8 waves x 64): w0 = poll batch0 + gate lanes (tid<32),
// w4 = poll batch1, w1-3 = m-tile 0..2 khalf0, w5-7 = m-tile 0..2 khalf1.
// Two __syncthreads per step. LDS padded to ~89KB to force 1 WG/CU so the
// DS pipe is not re-concentrated by multi-WG packing.
__global__ __launch_bounds__(512) void gru_kernel(const u16* __restrict__ Whh,
                                                  const float* __restrict__ b_hh,
                                                  const float* __restrict__ xproj,
                                                  unsigned* __restrict__ hbuf, // [2][2][1024] u32 tagged
                                                  float* __restrict__ states) { // [2][1024][1024]
  __shared__ __attribute__((aligned(16))) u16 lh[2 * 1024];      // stripped h (bf16)
  __shared__ __attribute__((aligned(16))) float hgsP[2][2][48];  // [khalf][batch][gate*16+ff]
  __shared__ u16 pad[42 * 1024];                                 // occupancy pad: 1 WG/CU
  const int g = blockIdx.x, tid = threadIdx.x;
  const int f0 = g * 16;
  const int w = tid >> 6, l = tid & 63;
  const int frow = l & 15, fq = l >> 4;

  pad[tid] = (u16)tid;                       // keep pad live
  asm volatile("" :: "v"((int)pad[tid ^ 1]));

  const bool isPoll = (w == 0) || (w == 4);
  const int pb = (w == 4) ? 1 : 0;           // poller batch
  const int m = (w >= 5) ? (w - 5) : (w - 1);   // compute m-tile (gate)
  const int half = (w >= 5) ? 1 : 0;
  const int k0 = half * 16;

  // A-frags resident in VGPRs: A[row = m*16+frow][k*32 + fq*8 .. +7]
  bf16x8 afr[16];
  if (!isPoll) {
    const u16* base = Whh + ((long)(m * 1024 + f0 + frow)) * 1024 + fq * 8;
#pragma unroll
    for (int kk = 0; kk < 16; kk++)
      afr[kk] = *(const bf16x8*)(base + (k0 + kk) * 32);
  }
  float bhr = 0.f, bhz = 0.f, bhn = 0.f, hp = 0.f;  // gate lanes: tid<32
  if (tid < 32) {
    int ff = tid & 15;
    bhr = b_hh[f0 + ff]; bhz = b_hh[1024 + f0 + ff]; bhn = b_hh[2048 + f0 + ff];
  }
  __syncthreads();

  for (int t = 0; t < 1024; t++) {
    // x-gate prefetch (independent of h; in flight during the poll)
    float xr = 0.f, xz = 0.f, xn = 0.f;
    if (tid < 32) {
      int bb = tid >> 4, ff = tid & 15;
      const float* xb = xproj + (long)((bb << 10) + t) * 3072 + f0 + ff;
      xr = xb[0]; xz = xb[1024]; xn = xb[2048];
    }
    if (isPoll) {
      // poll tagged h (R6 protocol): 8 u64/lane covering this batch's 4KB
      const u64* hb = (const u64*)hbuf + ((t & 1) << 10) + (pb << 9);
      const unsigned tg = (unsigned)t;
      u64 v[8];
      for (;;) {
        bool ok = true;
#pragma unroll
        for (int k = 0; k < 8; k++)
          v[k] = __hip_atomic_load(hb + (k << 6) + l, __ATOMIC_RELAXED, __HIP_MEMORY_SCOPE_AGENT);
#pragma unroll
        for (int k = 0; k < 8; k++)
          ok &= (((unsigned)v[k] >> 16) >= tg) & ((unsigned)(v[k] >> 48) >= tg);
        if (__all(ok)) break;
        __builtin_amdgcn_s_sleep(1);
      }
      // strip tags -> lh: u32 j holds cols 2j,2j+1 (bf16 pair)
      unsigned* lh32 = (unsigned*)lh;
#pragma unroll
      for (int k = 0; k < 8; k++)
        lh32[(pb << 9) + (k << 6) + l] =
            ((unsigned)v[k] & 0xffffu) | ((unsigned)(v[k] >> 32) << 16);
    }
    __syncthreads();                         // lh(t) visible to all
    if (!isPoll) {
      // 16 MFMAs: c += A(frag kk) * B(h frag kk). B: lane n=frow=batch col,
      // k-rows fq*8..+7; cols>=2 zeroed; col1..15 share batch1 addr (bcast).
      f32x4 c = (f32x4){0.f, 0.f, 0.f, 0.f};
      const int bsel = frow ? 1 : 0;
      const u16* bbase = lh + (bsel << 10) + fq * 8;
#pragma unroll
      for (int kk = 0; kk < 16; kk++) {
        union { uint4 u; bf16x8 b; } U;
        U.u = *(const uint4*)(bbase + (k0 + kk) * 32);
        if (frow >= 2) U.u = (uint4){0u, 0u, 0u, 0u};
        c = __builtin_amdgcn_mfma_f32_16x16x32_bf16(afr[kk], U.b, c, 0, 0, 0);
      }
      if (frow < 2)                          // C: col=batch, rows fq*4..+3
        *(f32x4*)&hgsP[half][frow][m * 16 + fq * 4] = c;
    }
    __syncthreads();                         // hgsP complete
    if (tid < 32) {
      int bb = tid >> 4, ff = tid & 15, f = f0 + ff;
      float hr = hgsP[0][bb][ff]      + hgsP[1][bb][ff];
      float hz = hgsP[0][bb][16 + ff] + hgsP[1][bb][16 + ff];
      float hn = hgsP[0][bb][32 + ff] + hgsP[1][bb][32 + ff];
      float rr = 1.f / (1.f + expf(-(xr + hr + bhr)));
      float zz = 1.f / (1.f + expf(-(xz + hz + bhz)));
      float nn = tanhf(xn + rr * (hn + bhn));
      float hnew = (1.f - zz) * nn + zz * hp;
      hp = hnew;
      states[(long)((bb << 10) + t) * 1024 + f] = hnew;
      unsigned word = ((unsigned)(t + 1) << 16) | (unsigned)f2bf(hnew);
      __hip_atomic_store(hbuf + (((t + 1) & 1) << 11) + (bb << 10) + f, word,
                         __ATOMIC_RELAXED, __HIP_MEMORY_SCOPE_AGENT);
    }
    // no 3rd barrier: lh(t+1) is only written by pollers after their poll
    // passes, which requires every WG's publish(t+1), which requires our gate
    // lanes to have finished reading hgsP(t); compute waves only write
    // hgsP(t+1) after the next first barrier, which pollers gate.
  }
}

// ---------------- mixed + RMSnorm + gate -------------------------------------
__global__ __launch_bounds__(256) void mix_kernel(const float* __restrict__ states,
                                                  const float* __restrict__ inres,
                                                  const float* __restrict__ gate_W,
                                                  const float* __restrict__ gate_b,
                                                  const float* __restrict__ rlam,
                                                  const float* __restrict__ ilam,
                                                  const float* __restrict__ mscale,
                                                  u16* __restrict__ mixed_bf,
                                                  float* __restrict__ gate6) {
  const int row = blockIdx.x, tid = threadIdx.x, w = tid >> 6, l = tid & 63;
  __shared__ float red[16];
  float rl = rlam[0], il = ilam[0];
  const float* sr = states + (long)row * 1024;
  const float* ir = inres + (long)row * 1024;
  float m[4]; float ss = 0.f;
#pragma unroll
  for (int u = 0; u < 4; u++) {
    int h = (u << 8) + tid;
    m[u] = rl * sr[h] + il * ir[h];
    ss += m[u] * m[u];
  }
#pragma unroll
  for (int off = 32; off > 0; off >>= 1) ss += __shfl_down(ss, off, 64);
  if (l == 0) red[w] = ss;
  __syncthreads();
  float tot = red[0] + red[1] + red[2] + red[3];
  float scale = rsqrtf(tot * (1.f / 1024.f) + 1.1920929e-07f);
  float gd = 0.f;
#pragma unroll
  for (int u = 0; u < 4; u++) {
    int h = (u << 8) + tid;
    float v = m[u] * scale;
    mixed_bf[(long)row * 1024 + h] = f2bf(v);
    gd += v * gate_W[h];
  }
#pragma unroll
  for (int off = 32; off > 0; off >>= 1) gd += __shfl_down(gd, off, 64);
  if (l == 0) red[8 + w] = gd;
  __syncthreads();
  if (tid == 0) {
    float gsum = red[8] + red[9] + red[10] + red[11] + gate_b[0];
    gate6[row] = (1.f / (1.f + expf(-gsum))) * mscale[0];
  }
}

// ---------------- strictly-causal softmax attention -> gated -----------------
__global__ __launch_bounds__(256) void attn_kernel(const float* __restrict__ q,
                                                   const float* __restrict__ k,
                                                   const float* __restrict__ gate6,
                                                   float* __restrict__ gated) {
  const int bi = blockIdx.x; const int b = bi >> 10, i = bi & 1023;
  if (i == 0) return;
  const int tid = threadIdx.x, w = tid >> 6, l = tid & 63;
  __shared__ float sc[1024];
  __shared__ float red[16];
  const float4 qv = *(const float4*)(q + (long)bi * 256 + (l << 2));
  for (int j = w; j < i; j += 4) {
    float4 kv = *(const float4*)(k + ((long)(b << 10) + j) * 256 + (l << 2));
    float s = qv.x * kv.x + qv.y * kv.y + qv.z * kv.z + qv.w * kv.w;
#pragma unroll
    for (int off = 32; off > 0; off >>= 1) s += __shfl_down(s, off, 64);
    if (l == 0) sc[j] = s * 0.0625f;       // 1/sqrt(256)
  }
  __syncthreads();
  float mx = -3.0e38f;
  for (int j = tid; j < i; j += 256) mx = fmaxf(mx, sc[j]);
#pragma unroll
  for (int off = 32; off > 0; off >>= 1) mx = fmaxf(mx, __shfl_down(mx, off, 64));
  if (l == 0) red[w] = mx;
  __syncthreads();
  mx = fmaxf(fmaxf(red[0], red[1]), fmaxf(red[2], red[3]));
  float sum = 0.f;
  for (int j = tid; j < i; j += 256) { float e = expf(sc[j] - mx); sc[j] = e; sum += e; }
#pragma unroll
  for (int off = 32; off > 0; off >>= 1) sum += __shfl_down(sum, off, 64);
  if (l == 0) red[8 + w] = sum;
  __syncthreads();
  sum = red[8] + red[9] + red[10] + red[11];
  float invs = gate6[bi] / sum;
  float* grow = gated + (long)bi * 1024;
  for (int j = tid; j < i; j += 256) grow[j] = sc[j] * invs;
}

// ---------------- scatter-add into logits ------------------------------------
__global__ __launch_bounds__(256) void scatter_kernel(const int* __restrict__ ids,
                                                      const float* __restrict__ gated,
                                                      float* __restrict__ out) {
  const int bi = blockIdx.x; const int b = bi >> 10, i = bi & 1023;
  const float* g = gated + (long)bi * 1024;
  float* o = out + (long)bi * 32000;
  const int* idr = ids + (b << 10);
  for (int j = threadIdx.x; j < i; j += 256)
    atomicAdd(o + idr[j], g[j]);
}

extern "C" void kernel_launch(void* const* d_in, const int* in_sizes, int n_in,
                              void* d_out, int out_size, void* d_ws, size_t ws_size,
                              hipStream_t stream) {
  const int*   ids      = (const int*)  d_in[0];
  const float* emb_W    = (const float*)d_in[1];
  const float* W_ih     = (const float*)d_in[2];
  const float* W_hh     = (const float*)d_in[3];
  const float* b_ih     = (const float*)d_in[4];
  const float* b_hh     = (const float*)d_in[5];
  const float* in_res_W = (const float*)d_in[6];
  const float* q_W      = (const float*)d_in[7];
  const float* q_b      = (const float*)d_in[8];
  const float* k_W      = (const float*)d_in[9];
  const float* k_b      = (const float*)d_in[10];
  const float* gate_W   = (const float*)d_in[11];
  const float* gate_b   = (const float*)d_in[12];
  const float* h2e_W    = (const float*)d_in[13];
  const float* h2e_b    = (const float*)d_in[14];
  const float* out_bias = (const float*)d_in[15];
  const float* mscale   = (const float*)d_in[16];
  const float* rlam     = (const float*)d_in[17];
  const float* ilam     = (const float*)d_in[18];
  float* out = (float*)d_out;

  char* p = (char*)d_ws;
  auto alloc = [&](size_t b) { char* r = p; p += (b + 255) & ~(size_t)255; return (void*)r; };
  u16*   emb_bf   = (u16*)  alloc((size_t)2048 * 512 * 2);
  u16*   Wih_bf   = (u16*)  alloc((size_t)3072 * 512 * 2);
  u16*   inresW_bf= (u16*)  alloc((size_t)1024 * 512 * 2);
  u16*   Whh_bf   = (u16*)  alloc((size_t)3072 * 1024 * 2);
  u16*   h2e_bf   = (u16*)  alloc((size_t)512 * 1024 * 2);
  u16*   qW_bf    = (u16*)  alloc((size_t)256 * 1024 * 2);
  u16*   kW_bf    = (u16*)  alloc((size_t)256 * 1024 * 2);
  u16*   embW_bf  = (u16*)  alloc((size_t)32000 * 512 * 2);
  float* xproj    = (float*)alloc((size_t)2048 * 3072 * 4);
  float* inres    = (float*)alloc((size_t)2048 * 1024 * 4);
  float* states   = (float*)alloc((size_t)2048 * 1024 * 4);
  u16*   mixed_bf = (u16*)  alloc((size_t)2048 * 1024 * 2);
  float* tbuf     = (float*)alloc((size_t)2048 * 512 * 4);
  u16*   t_bf     = (u16*)  alloc((size_t)2048 * 512 * 2);
  float* qbuf     = (float*)alloc((size_t)2048 * 256 * 4);
  float* kbuf     = (float*)alloc((size_t)2048 * 256 * 4);
  float* gated    = (float*)alloc((size_t)2048 * 1024 * 4);
  float* gate6    = (float*)alloc((size_t)2048 * 4);
  unsigned* hbuf  = (unsigned*)alloc((size_t)2 * 2 * 1024 * 4);

  hipMemsetAsync(hbuf, 0, 2 * 2 * 1024 * 4, stream);

  // weight / input conversions to bf16
  f2bf_kernel<<<1024, 256, 0, stream>>>(W_ih, Wih_bf, 3072 * 512);
  f2bf_kernel<<<512, 256, 0, stream>>>(in_res_W, inresW_bf, 1024 * 512);
  f2bf_kernel<<<1024, 256, 0, stream>>>(W_hh, Whh_bf, 3072 * 1024);
  f2bf_kernel<<<512, 256, 0, stream>>>(h2e_W, h2e_bf, 512 * 1024);
  f2bf_kernel<<<256, 256, 0, stream>>>(q_W, qW_bf, 256 * 1024);
  f2bf_kernel<<<256, 256, 0, stream>>>(k_W, kW_bf, 256 * 1024);
  f2bf_kernel<<<2048, 256, 0, stream>>>(emb_W, embW_bf, 32000 * 512);
  gather_kernel<<<2048, 256, 0, stream>>>(ids, emb_W, emb_bf);

  // x_proj = emb @ W_ih.T + b_ih ;  inres = emb @ in_res_W.T
  gemm_bt<<<dim3(24, 16), 256, 0, stream>>>(emb_bf, Wih_bf, xproj, b_ih, 2048, 3072, 512);
  gemm_bt<<<dim3(8, 16), 256, 0, stream>>>(emb_bf, inresW_bf, inres, nullptr, 2048, 1024, 512);

  // sequential GRU over S=1024 (flag-in-data sync + MFMA core, 64 WGs)
  gru_kernel<<<64, 512, 0, stream>>>(Whh_bf, b_hh, xproj, hbuf, states);

  // mixed + RMS + gate
  mix_kernel<<<2048, 256, 0, stream>>>(states, inres, gate_W, gate_b, rlam, ilam, mscale,
                                       mixed_bf, gate6);

  // q, k, t projections
  gemm_bt<<<dim3(2, 16), 256, 0, stream>>>(mixed_bf, qW_bf, qbuf, q_b, 2048, 256, 1024);
  gemm_bt<<<dim3(2, 16), 256, 0, stream>>>(mixed_bf, kW_bf, kbuf, k_b, 2048, 256, 1024);
  gemm_bt<<<dim3(4, 16), 256, 0, stream>>>(mixed_bf, h2e_bf, tbuf, h2e_b, 2048, 512, 1024);
  f2bf_kernel<<<512, 256, 0, stream>>>(tbuf, t_bf, 2048 * 512);

  // attention -> gated
  attn_kernel<<<2048, 256, 0, stream>>>(qbuf, kbuf, gate6, gated);

  // base logits (big GEMM, writes all of d_out) then scatter-add
  gemm_bt<<<dim3(250, 16), 256, 0, stream>>>(t_bf, embW_bf, out, out_bias, 2048, 32000, 512);
  scatter_kernel<<<2048, 256, 0, stream>>>(ids, gated, out);
}